// Round 9
// baseline (230.385 us; speedup 1.0000x reference)
//
#include <hip/hip_runtime.h>
#include <hip/hip_bf16.h>

#define NROWS 8192
#define DEMB 256
#define MARGIN 0.2f
#define NCLS 512
#define TPC 8                    // B tiles (128 cols) per chunk
#define NSTEP 32                 // 8 tiles * 4 quarter-K steps (BK=64)
#define MCAP 64                  // max class size (mean 16, 12 sigma)
#define SROW 264                 // padded LDS row stride (ushorts) for k_cpairs2

typedef __attribute__((ext_vector_type(4))) float f32x4;
typedef __attribute__((ext_vector_type(8))) short bf16x8;

static __device__ __forceinline__ unsigned short f2b(float f) {
    unsigned u = __builtin_bit_cast(unsigned, f);
    u += 0x7fffu + ((u >> 16) & 1u);           // RNE round to bf16
    return (unsigned short)(u >> 16);
}
static __device__ __forceinline__ float b2f(unsigned short b) {
    unsigned u = ((unsigned)b) << 16;
    return __builtin_bit_cast(float, u);
}
// order-preserving f32 -> u32 encode (max-compatible; finite values never encode to 0)
static __device__ __forceinline__ unsigned encf(float f) {
    unsigned u = __builtin_bit_cast(unsigned, f);
    return (u & 0x80000000u) ? ~u : (u | 0x80000000u);
}
static __device__ __forceinline__ float decf(unsigned e) {
    unsigned u = (e & 0x80000000u) ? (e ^ 0x80000000u) : ~e;
    return __builtin_bit_cast(float, u);
}
static __device__ __forceinline__ void gload16(const void* g, void* l) {
    __builtin_amdgcn_global_load_lds(
        (const __attribute__((address_space(1))) unsigned int*)g,
        (__attribute__((address_space(3))) unsigned int*)l, 16, 0, 0);
}

// K1: row-L2-normalize fp32 -> bf16; zero amax; bucket rows by class.
__global__ __launch_bounds__(256) void k_norm(const float* __restrict__ x,
                                              const int* __restrict__ labels,
                                              unsigned short* __restrict__ xnb,
                                              unsigned* __restrict__ amax,
                                              int* __restrict__ bcnt,
                                              int* __restrict__ mem) {
    int gid = blockIdx.x * blockDim.x + threadIdx.x;
    if (gid < NROWS) {
        amax[gid] = 0u;
        int l = labels[gid];
        int slot = atomicAdd(&bcnt[l], 1);
        if (slot < MCAP) mem[l * MCAP + slot] = gid;
    }
    int row  = gid >> 6;
    int lane = threadIdx.x & 63;
    const float4* p = reinterpret_cast<const float4*>(x + (size_t)row * DEMB) + lane;
    float4 v = *p;
    float s = v.x * v.x + v.y * v.y + v.z * v.z + v.w * v.w;
#pragma unroll
    for (int m = 1; m < 64; m <<= 1) s += __shfl_xor(s, m);
    float inv = 1.0f / fmaxf(sqrtf(s), 1e-8f);
    ushort4 o;
    o.x = f2b(v.x * inv); o.y = f2b(v.y * inv);
    o.z = f2b(v.z * inv); o.w = f2b(v.w * inv);
    *(reinterpret_cast<ushort4*>(xnb + (size_t)row * DEMB) + lane) = o;
}

// K2: strip-streaming MFMA row-max with counted-vmcnt deep pipeline (T3+T4).
// 4 x 16KB LDS buffers, BK=64, 32 steps, 3-deep prefetch, raw s_barrier +
// s_waitcnt vmcnt(6) (never 0 in steady state). Double barrier per step makes
// buffer reuse race-free by construction. A-strip in registers (full K).
__global__ __launch_bounds__(512, 4) void k_maxneg(const unsigned short* __restrict__ xnb,
                                                   const int* __restrict__ labels,
                                                   unsigned* __restrict__ amax) {
    extern __shared__ char lds[];
    unsigned short* Bl = (unsigned short*)lds;   // 4 bufs x 16KB
    const char* BlC = (const char*)lds;

    int tid  = threadIdx.x;
    int wid  = tid >> 6, lane = tid & 63;
    int wr   = wid >> 1, wc = wid & 1;           // 4 row-subwaves x 2 col-subwaves
    int arow = lane & 15, kgrp = lane >> 4;

    int i0 = blockIdx.x * 128;
    int j0 = blockIdx.y * (TPC * 128);

    // A fragments in registers: row = i0 + wr*32 + m*16 + arow, k-slice ks=0..7
    bf16x8 a[2][8];
    const unsigned short* ap0 = xnb + (size_t)(i0 + wr * 32 + arow) * DEMB + kgrp * 8;
#pragma unroll
    for (int m = 0; m < 2; ++m)
#pragma unroll
        for (int kk = 0; kk < 8; ++kk)
            a[m][kk] = *(const bf16x8*)(ap0 + m * 16 * DEMB + kk * 32);

    int rlab[2][4];
#pragma unroll
    for (int m = 0; m < 2; ++m)
#pragma unroll
        for (int r = 0; r < 4; ++r)
            rlab[m][r] = labels[i0 + wr * 32 + m * 16 + kgrp * 4 + r];

    // staging bases: thread owns 16B chunks tid and tid+512 of each 16KB buf
    int row0  = tid >> 3;                        // 8 chunks per 128B row
    int colb0 = (tid & 7) << 4;
    int scol0 = (colb0 ^ ((row0 & 7) << 4)) >> 1;   // pre-swizzled elem col
    const unsigned short* sb = xnb + (size_t)(j0 + row0) * DEMB + scol0;
    unsigned short* db = Bl + wid * 512;         // HW adds lane*16B

    // swizzled ds_read byte offsets (ksl = 0,1 within BK=64)
    int sx  = (arow & 7) << 4;
    int rb0 = (wc * 64 + arow) * 128;
    int rc0 = rb0 + ((kgrp * 16) ^ sx);
    int rc1 = rb0 + ((64 + kgrp * 16) ^ sx);

    float rmax[2][4] = {{-1e30f, -1e30f, -1e30f, -1e30f},
                        {-1e30f, -1e30f, -1e30f, -1e30f}};
    f32x4 acc[2][4] = {};
    int clab[4], nlab[4];
#pragma unroll
    for (int n = 0; n < 4; ++n) clab[n] = labels[j0 + wc * 64 + n * 16 + arow];

// stage quarter-tile S: tile t=S>>2, k-quarter ks=S&3 -> buf S&3 (16KB)
#define STAGE(S) { \
        const unsigned short* s_ = sb + ((S) >> 2) * 32768 + ((S) & 3) * 64; \
        unsigned short* d_ = db + ((S) & 3) * 8192; \
        gload16(s_, d_); \
        gload16(s_ + 16384, d_ + 4096); }

    STAGE(0) STAGE(1) STAGE(2)

#pragma unroll
    for (int s = 0; s < NSTEP; ++s) {
        if (s + 3 < NSTEP) STAGE(s + 3)
        if ((s & 3) == 0 && (s >> 2) + 1 < TPC) {
#pragma unroll
            for (int n = 0; n < 4; ++n)
                nlab[n] = labels[j0 + ((s >> 2) + 1) * 128 + wc * 64 + n * 16 + arow];
        }
        // counted wait: 3 stage-groups (6 loads) may remain in flight
        if (s < NSTEP - 3)      asm volatile("s_waitcnt vmcnt(6)" ::: "memory");
        else if (s == NSTEP - 3) asm volatile("s_waitcnt vmcnt(4)" ::: "memory");
        else if (s == NSTEP - 2) asm volatile("s_waitcnt vmcnt(2)" ::: "memory");
        else                     asm volatile("s_waitcnt vmcnt(0)" ::: "memory");
        __builtin_amdgcn_sched_barrier(0);
        __builtin_amdgcn_s_barrier();            // buf[s&3] ready for all waves
        __builtin_amdgcn_sched_barrier(0);
        {
            const char* Bt = BlC + (s & 3) * 16384;
            bf16x8 b[4][2];
#pragma unroll
            for (int n = 0; n < 4; ++n) {
                b[n][0] = *(const bf16x8*)(Bt + n * 2048 + rc0);
                b[n][1] = *(const bf16x8*)(Bt + n * 2048 + rc1);
            }
            __builtin_amdgcn_s_setprio(1);
#pragma unroll
            for (int m = 0; m < 2; ++m)
#pragma unroll
                for (int n = 0; n < 4; ++n) {
                    acc[m][n] = __builtin_amdgcn_mfma_f32_16x16x32_bf16(
                        a[m][(s & 3) * 2], b[n][0], acc[m][n], 0, 0, 0);
                    acc[m][n] = __builtin_amdgcn_mfma_f32_16x16x32_bf16(
                        a[m][(s & 3) * 2 + 1], b[n][1], acc[m][n], 0, 0, 0);
                }
            __builtin_amdgcn_s_setprio(0);
        }
        __builtin_amdgcn_sched_barrier(0);
        __builtin_amdgcn_s_barrier();            // all reads consumed: buf reusable
        if ((s & 3) == 3) {                      // tile boundary: masked fold
#pragma unroll
            for (int m = 0; m < 2; ++m)
#pragma unroll
                for (int r = 0; r < 4; ++r) {
                    float v = rmax[m][r];
                    int rl = rlab[m][r];
#pragma unroll
                    for (int n = 0; n < 4; ++n)
                        if (clab[n] != rl) v = fmaxf(v, acc[m][n][r]);
                    rmax[m][r] = v;
                }
#pragma unroll
            for (int m = 0; m < 2; ++m)
#pragma unroll
                for (int n = 0; n < 4; ++n) acc[m][n] = (f32x4){0.f, 0.f, 0.f, 0.f};
#pragma unroll
            for (int n = 0; n < 4; ++n) clab[n] = nlab[n];
        }
    }
#undef STAGE

    // Reduce over 16 col-lanes, combine wc pair via LDS, one atomic per row.
    float* smax = (float*)Bl;                    // buf0 dead after final barrier
#pragma unroll
    for (int m = 0; m < 2; ++m)
#pragma unroll
        for (int r = 0; r < 4; ++r) {
            float v = rmax[m][r];
#pragma unroll
            for (int msk = 1; msk < 16; msk <<= 1) v = fmaxf(v, __shfl_xor(v, msk));
            if (arow == 0) smax[wc * 128 + wr * 32 + m * 16 + kgrp * 4 + r] = v;
        }
    __syncthreads();
    if (tid < 128) {
        float v = fmaxf(smax[tid], smax[128 + tid]);
        if (v > -1e29f) atomicMax(amax + i0 + tid, encf(v));
    }
}

// K3: per-class pair losses + fused global finalize (last block writes out).
__global__ __launch_bounds__(256) void k_cpairs2(const unsigned short* __restrict__ xnb,
                                                 const unsigned* __restrict__ amax,
                                                 const int* __restrict__ bcnt,
                                                 const int* __restrict__ mem,
                                                 float* __restrict__ gsum,
                                                 int* __restrict__ gcnt,
                                                 unsigned* __restrict__ done,
                                                 float* __restrict__ out) {
    __shared__ unsigned short srows[MCAP * SROW];
    __shared__ int mlist[MCAP];
    __shared__ float sdm[MCAP];
    __shared__ unsigned char shn[MCAP];
    __shared__ float slloss[16];
    __shared__ int slcnt[16];

    int c   = blockIdx.x;
    int tid = threadIdx.x;
    int nc  = bcnt[c];
    if (nc > MCAP) nc = MCAP;

    if (tid < nc) {
        int gi = mem[c * MCAP + tid];
        mlist[tid] = gi;
        unsigned e = amax[gi];
        shn[tid] = (e != 0u);
        sdm[tid] = 1.0f - decf(e);
    }
    __syncthreads();
    int nch = nc * 32;
    for (int ch = tid; ch < nch; ch += 256) {
        int r = ch >> 5, cc = ch & 31;
        *(bf16x8*)(srows + r * SROW + cc * 8) =
            *(const bf16x8*)(xnb + (size_t)mlist[r] * DEMB + cc * 8);
    }
    __syncthreads();

    int slot = tid >> 4, gl = tid & 15;
    int npairs = nc * (nc - 1) / 2;
    float gloss = 0.f;
    int gc = 0;
    for (int p = slot; p < npairs; p += 16) {
        int i = 0, rem = p;
        while (rem >= nc - 1 - i) { rem -= nc - 1 - i; ++i; }
        int j = i + 1 + rem;
        bf16x8 a0 = *(const bf16x8*)(srows + i * SROW + gl * 16);
        bf16x8 a1 = *(const bf16x8*)(srows + i * SROW + gl * 16 + 8);
        bf16x8 b0 = *(const bf16x8*)(srows + j * SROW + gl * 16);
        bf16x8 b1 = *(const bf16x8*)(srows + j * SROW + gl * 16 + 8);
        float dot = 0.f;
#pragma unroll
        for (int e = 0; e < 8; ++e) {
            dot += b2f((unsigned short)a0[e]) * b2f((unsigned short)b0[e]);
            dot += b2f((unsigned short)a1[e]) * b2f((unsigned short)b1[e]);
        }
#pragma unroll
        for (int msk = 1; msk < 16; msk <<= 1) dot += __shfl_xor(dot, msk);
        if (gl == 0) {
            int ai = (mlist[i] < mlist[j]) ? i : j;      // anchor = min global idx
            if (shn[ai]) {
                gloss += fmaxf(1.0f - dot - sdm[ai] + MARGIN, 0.0f);
                gc += 1;
            }
        }
    }
    if (gl == 0) { slloss[slot] = gloss; slcnt[slot] = gc; }
    __syncthreads();
    if (tid == 0) {
        float s = 0.f; int k = 0;
        for (int q = 0; q < 16; ++q) { s += slloss[q]; k += slcnt[q]; }
        atomicAdd(gsum, s);
        atomicAdd(gcnt, k);
        __threadfence();
        unsigned old = atomicAdd(done, 1u);
        if (old == NCLS - 1) {                   // last block finalizes
            float S = atomicAdd(gsum, 0.0f);
            int   K = atomicAdd(gcnt, 0);
            out[0] = (K > 0) ? S / (float)K : 0.0f;
            out[1] = (float)K;
        }
    }
}

extern "C" void kernel_launch(void* const* d_in, const int* in_sizes, int n_in,
                              void* d_out, int out_size, void* d_ws, size_t ws_size,
                              hipStream_t stream) {
    const float* emb  = (const float*)d_in[0];
    const int* labels = (const int*)d_in[1];
    float* out = (float*)d_out;

    char* ws = (char*)d_ws;
    unsigned short* xnb = (unsigned short*)ws;                            // 4 MB
    unsigned* amax = (unsigned*)(ws + (size_t)4 * 1024 * 1024);           // 32 KB
    int*      bcnt = (int*)     (ws + (size_t)4 * 1024 * 1024 + 32768);   // 2048 B
    float*    gsum = (float*)   (ws + (size_t)4 * 1024 * 1024 + 34816);   // 4 B
    int*      gcnt = (int*)     (ws + (size_t)4 * 1024 * 1024 + 34820);   // 4 B
    unsigned* done = (unsigned*)(ws + (size_t)4 * 1024 * 1024 + 34824);   // 4 B
    int*      mem  = (int*)     (ws + (size_t)4 * 1024 * 1024 + 36864);   // 128 KB

    hipMemsetAsync(bcnt, 0, 2048 + 16, stream);          // bcnt + gsum/gcnt/done
    k_norm<<<NROWS / 4, 256, 0, stream>>>(emb, labels, xnb, amax, bcnt, mem);
    dim3 g2(NROWS / 128, NCLS / 64);   // 64 strips x 8 chunks
    k_maxneg<<<g2, 512, 65536, stream>>>(xnb, labels, amax);
    k_cpairs2<<<NCLS, 256, 0, stream>>>(xnb, amax, bcnt, mem, gsum, gcnt, done, out);
}

// Round 10
// 87.234 us; speedup vs baseline: 2.6410x; 2.6410x over previous
//
#include <hip/hip_runtime.h>
#include <hip/hip_bf16.h>

#define NROWS 8192
#define DEMB 256
#define MARGIN 0.2f
#define NCLS 512
#define TPC 8                    // B tiles (128 cols) per chunk
#define MCAP 64                  // max class size (mean 16, 12 sigma)
#define SROW 264                 // padded LDS row stride (ushorts) for k_cpairs2

typedef __attribute__((ext_vector_type(4))) float f32x4;
typedef __attribute__((ext_vector_type(8))) short bf16x8;

static __device__ __forceinline__ unsigned short f2b(float f) {
    unsigned u = __builtin_bit_cast(unsigned, f);
    u += 0x7fffu + ((u >> 16) & 1u);           // RNE round to bf16
    return (unsigned short)(u >> 16);
}
static __device__ __forceinline__ float b2f(unsigned short b) {
    unsigned u = ((unsigned)b) << 16;
    return __builtin_bit_cast(float, u);
}
// order-preserving f32 -> u32 encode (max-compatible; finite values never encode to 0)
static __device__ __forceinline__ unsigned encf(float f) {
    unsigned u = __builtin_bit_cast(unsigned, f);
    return (u & 0x80000000u) ? ~u : (u | 0x80000000u);
}
static __device__ __forceinline__ float decf(unsigned e) {
    unsigned u = (e & 0x80000000u) ? (e ^ 0x80000000u) : ~e;
    return __builtin_bit_cast(float, u);
}
static __device__ __forceinline__ void gload16(const void* g, void* l) {
    __builtin_amdgcn_global_load_lds(
        (const __attribute__((address_space(1))) unsigned int*)g,
        (__attribute__((address_space(3))) unsigned int*)l, 16, 0, 0);
}

// K1: row-L2-normalize fp32 -> bf16; zero amax; bucket rows by class.
__global__ __launch_bounds__(256) void k_norm(const float* __restrict__ x,
                                              const int* __restrict__ labels,
                                              unsigned short* __restrict__ xnb,
                                              unsigned* __restrict__ amax,
                                              int* __restrict__ bcnt,
                                              int* __restrict__ mem) {
    int gid = blockIdx.x * blockDim.x + threadIdx.x;
    if (gid < NROWS) {
        amax[gid] = 0u;
        int l = labels[gid];
        int slot = atomicAdd(&bcnt[l], 1);
        if (slot < MCAP) mem[l * MCAP + slot] = gid;
    }
    int row  = gid >> 6;
    int lane = threadIdx.x & 63;
    const float4* p = reinterpret_cast<const float4*>(x + (size_t)row * DEMB) + lane;
    float4 v = *p;
    float s = v.x * v.x + v.y * v.y + v.z * v.z + v.w * v.w;
#pragma unroll
    for (int m = 1; m < 64; m <<= 1) s += __shfl_xor(s, m);
    float inv = 1.0f / fmaxf(sqrtf(s), 1e-8f);
    ushort4 o;
    o.x = f2b(v.x * inv); o.y = f2b(v.y * inv);
    o.z = f2b(v.z * inv); o.w = f2b(v.w * inv);
    *(reinterpret_cast<ushort4*>(xnb + (size_t)row * DEMB) + lane) = o;
}

// K2: strip-streaming MFMA row-max, counted-vmcnt deep pipeline (T3+T4).
// 4 x 16KB LDS buffers, BK=64, 3-deep prefetch, raw s_barrier + vmcnt(6)
// (never 0 in steady state). launch_bounds(512,2): VGPR cap 256 (r9's (512,4)
// capped at 128 -> spill catastrophe). t-loop runtime, quarters explicit.
__global__ __launch_bounds__(512, 2) void k_maxneg(const unsigned short* __restrict__ xnb,
                                                   const int* __restrict__ labels,
                                                   unsigned* __restrict__ amax) {
    extern __shared__ char lds[];
    unsigned short* Bl = (unsigned short*)lds;   // 4 bufs x 16KB
    const char* BlC = (const char*)lds;

    int tid  = threadIdx.x;
    int wid  = tid >> 6, lane = tid & 63;
    int wr   = wid >> 1, wc = wid & 1;           // 4 row-subwaves x 2 col-subwaves
    int arow = lane & 15, kgrp = lane >> 4;

    int i0 = blockIdx.x * 128;
    int j0 = blockIdx.y * (TPC * 128);

    // A fragments in registers: row = i0 + wr*32 + m*16 + arow, k-slice kk=0..7
    bf16x8 a[2][8];
    const unsigned short* ap0 = xnb + (size_t)(i0 + wr * 32 + arow) * DEMB + kgrp * 8;
#pragma unroll
    for (int m = 0; m < 2; ++m)
#pragma unroll
        for (int kk = 0; kk < 8; ++kk)
            a[m][kk] = *(const bf16x8*)(ap0 + m * 16 * DEMB + kk * 32);

    int rlab[2][4];
#pragma unroll
    for (int m = 0; m < 2; ++m)
#pragma unroll
        for (int r = 0; r < 4; ++r)
            rlab[m][r] = labels[i0 + wr * 32 + m * 16 + kgrp * 4 + r];

    // staging bases: thread owns 16B chunks tid and tid+512 of each 16KB buf
    int row0  = tid >> 3;                        // 8 chunks per 128B row
    int colb0 = (tid & 7) << 4;
    int scol0 = (colb0 ^ ((row0 & 7) << 4)) >> 1;   // pre-swizzled elem col
    const unsigned short* sbt = xnb + (size_t)(j0 + row0) * DEMB + scol0;
    unsigned short* db = Bl + wid * 512;         // HW adds lane*16B

    // swizzled ds_read byte offsets (k-halves within BK=64)
    int sx  = (arow & 7) << 4;
    int rb0 = (wc * 64 + arow) * 128;
    int rc0 = rb0 + ((kgrp * 16) ^ sx);
    int rc1 = rb0 + ((64 + kgrp * 16) ^ sx);

    float rmax[2][4] = {{-1e30f, -1e30f, -1e30f, -1e30f},
                        {-1e30f, -1e30f, -1e30f, -1e30f}};
    f32x4 acc[2][4] = {};
    int clab[4], nlab[4];
#pragma unroll
    for (int n = 0; n < 4; ++n) clab[n] = labels[j0 + wc * 64 + n * 16 + arow];

// stage quarter (TOFF tiles ahead of sbt, quarter QQ) into buf QQ
#define STAGE_T(TOFF, QQ) { \
        const unsigned short* s_ = sbt + (TOFF) * 32768 + (QQ) * 64; \
        unsigned short* d_ = db + (QQ) * 8192; \
        gload16(s_, d_); \
        gload16(s_ + 16384, d_ + 4096); }

// wait WC, barrier, ds_read buf QQ, MFMA with a-slices 2*QQ, 2*QQ+1, barrier
#define QCOMP(QQ, WC) { \
        asm volatile("s_waitcnt vmcnt(" #WC ")" ::: "memory"); \
        __builtin_amdgcn_sched_barrier(0); \
        __builtin_amdgcn_s_barrier(); \
        __builtin_amdgcn_sched_barrier(0); \
        const char* Bt = BlC + (QQ) * 16384; \
        bf16x8 b[4][2]; \
        _Pragma("unroll") \
        for (int n = 0; n < 4; ++n) { \
            b[n][0] = *(const bf16x8*)(Bt + n * 2048 + rc0); \
            b[n][1] = *(const bf16x8*)(Bt + n * 2048 + rc1); \
        } \
        __builtin_amdgcn_s_setprio(1); \
        _Pragma("unroll") \
        for (int m = 0; m < 2; ++m) \
            _Pragma("unroll") \
            for (int n = 0; n < 4; ++n) { \
                acc[m][n] = __builtin_amdgcn_mfma_f32_16x16x32_bf16( \
                    a[m][(QQ) * 2], b[n][0], acc[m][n], 0, 0, 0); \
                acc[m][n] = __builtin_amdgcn_mfma_f32_16x16x32_bf16( \
                    a[m][(QQ) * 2 + 1], b[n][1], acc[m][n], 0, 0, 0); \
            } \
        __builtin_amdgcn_s_setprio(0); \
        __builtin_amdgcn_sched_barrier(0); \
        __builtin_amdgcn_s_barrier(); }

#define TILEFOLD { \
        _Pragma("unroll") \
        for (int m = 0; m < 2; ++m) \
            _Pragma("unroll") \
            for (int r = 0; r < 4; ++r) { \
                float v = rmax[m][r]; \
                int rl = rlab[m][r]; \
                _Pragma("unroll") \
                for (int n = 0; n < 4; ++n) \
                    if (clab[n] != rl) v = fmaxf(v, acc[m][n][r]); \
                rmax[m][r] = v; \
            } \
        _Pragma("unroll") \
        for (int m = 0; m < 2; ++m) \
            _Pragma("unroll") \
            for (int n = 0; n < 4; ++n) acc[m][n] = (f32x4){0.f, 0.f, 0.f, 0.f}; \
        _Pragma("unroll") \
        for (int n = 0; n < 4; ++n) clab[n] = nlab[n]; }

    // prologue: stage quarters 0,1,2 of tile 0
    STAGE_T(0, 0) STAGE_T(0, 1) STAGE_T(0, 2)

    for (int t = 0; t < TPC - 1; ++t) {          // t = 0..6, steady state
#pragma unroll
        for (int n = 0; n < 4; ++n)
            nlab[n] = labels[j0 + (t + 1) * 128 + wc * 64 + n * 16 + arow];
        STAGE_T(0, 3) QCOMP(0, 6)                // q0: stage (t,q3),   compute buf0
        STAGE_T(1, 0) QCOMP(1, 6)                // q1: stage (t+1,q0), compute buf1
        STAGE_T(1, 1) QCOMP(2, 6)                // q2: stage (t+1,q1), compute buf2
        STAGE_T(1, 2) QCOMP(3, 6)                // q3: stage (t+1,q2), compute buf3
        TILEFOLD
        sbt += 32768;
    }
    // peeled last tile (t = 7): drain
    STAGE_T(0, 3) QCOMP(0, 6)
    QCOMP(1, 4)
    QCOMP(2, 2)
    QCOMP(3, 0)
    TILEFOLD
#undef STAGE_T
#undef QCOMP
#undef TILEFOLD

    // Reduce over 16 col-lanes, combine wc pair via LDS, one atomic per row.
    float* smax = (float*)Bl;                    // buf0 dead after final barrier
#pragma unroll
    for (int m = 0; m < 2; ++m)
#pragma unroll
        for (int r = 0; r < 4; ++r) {
            float v = rmax[m][r];
#pragma unroll
            for (int msk = 1; msk < 16; msk <<= 1) v = fmaxf(v, __shfl_xor(v, msk));
            if (arow == 0) smax[wc * 128 + wr * 32 + m * 16 + kgrp * 4 + r] = v;
        }
    __syncthreads();
    if (tid < 128) {
        float v = fmaxf(smax[tid], smax[128 + tid]);
        if (v > -1e29f) atomicMax(amax + i0 + tid, encf(v));
    }
}

// K3: per-class pair losses + fused global finalize (last block writes out).
__global__ __launch_bounds__(256) void k_cpairs2(const unsigned short* __restrict__ xnb,
                                                 const unsigned* __restrict__ amax,
                                                 const int* __restrict__ bcnt,
                                                 const int* __restrict__ mem,
                                                 float* __restrict__ gsum,
                                                 int* __restrict__ gcnt,
                                                 unsigned* __restrict__ done,
                                                 float* __restrict__ out) {
    __shared__ unsigned short srows[MCAP * SROW];
    __shared__ int mlist[MCAP];
    __shared__ float sdm[MCAP];
    __shared__ unsigned char shn[MCAP];
    __shared__ float slloss[16];
    __shared__ int slcnt[16];

    int c   = blockIdx.x;
    int tid = threadIdx.x;
    int nc  = bcnt[c];
    if (nc > MCAP) nc = MCAP;

    if (tid < nc) {
        int gi = mem[c * MCAP + tid];
        mlist[tid] = gi;
        unsigned e = amax[gi];
        shn[tid] = (e != 0u);
        sdm[tid] = 1.0f - decf(e);
    }
    __syncthreads();
    int nch = nc * 32;
    for (int ch = tid; ch < nch; ch += 256) {
        int r = ch >> 5, cc = ch & 31;
        *(bf16x8*)(srows + r * SROW + cc * 8) =
            *(const bf16x8*)(xnb + (size_t)mlist[r] * DEMB + cc * 8);
    }
    __syncthreads();

    int slot = tid >> 4, gl = tid & 15;
    int npairs = nc * (nc - 1) / 2;
    float gloss = 0.f;
    int gc = 0;
    for (int p = slot; p < npairs; p += 16) {
        int i = 0, rem = p;
        while (rem >= nc - 1 - i) { rem -= nc - 1 - i; ++i; }
        int j = i + 1 + rem;
        bf16x8 a0 = *(const bf16x8*)(srows + i * SROW + gl * 16);
        bf16x8 a1 = *(const bf16x8*)(srows + i * SROW + gl * 16 + 8);
        bf16x8 b0 = *(const bf16x8*)(srows + j * SROW + gl * 16);
        bf16x8 b1 = *(const bf16x8*)(srows + j * SROW + gl * 16 + 8);
        float dot = 0.f;
#pragma unroll
        for (int e = 0; e < 8; ++e) {
            dot += b2f((unsigned short)a0[e]) * b2f((unsigned short)b0[e]);
            dot += b2f((unsigned short)a1[e]) * b2f((unsigned short)b1[e]);
        }
#pragma unroll
        for (int msk = 1; msk < 16; msk <<= 1) dot += __shfl_xor(dot, msk);
        if (gl == 0) {
            int ai = (mlist[i] < mlist[j]) ? i : j;      // anchor = min global idx
            if (shn[ai]) {
                gloss += fmaxf(1.0f - dot - sdm[ai] + MARGIN, 0.0f);
                gc += 1;
            }
        }
    }
    if (gl == 0) { slloss[slot] = gloss; slcnt[slot] = gc; }
    __syncthreads();
    if (tid == 0) {
        float s = 0.f; int k = 0;
        for (int q = 0; q < 16; ++q) { s += slloss[q]; k += slcnt[q]; }
        atomicAdd(gsum, s);
        atomicAdd(gcnt, k);
        __threadfence();
        unsigned old = atomicAdd(done, 1u);
        if (old == NCLS - 1) {                   // last block finalizes
            float S = atomicAdd(gsum, 0.0f);
            int   K = atomicAdd(gcnt, 0);
            out[0] = (K > 0) ? S / (float)K : 0.0f;
            out[1] = (float)K;
        }
    }
}

extern "C" void kernel_launch(void* const* d_in, const int* in_sizes, int n_in,
                              void* d_out, int out_size, void* d_ws, size_t ws_size,
                              hipStream_t stream) {
    const float* emb  = (const float*)d_in[0];
    const int* labels = (const int*)d_in[1];
    float* out = (float*)d_out;

    char* ws = (char*)d_ws;
    unsigned short* xnb = (unsigned short*)ws;                            // 4 MB
    unsigned* amax = (unsigned*)(ws + (size_t)4 * 1024 * 1024);           // 32 KB
    int*      bcnt = (int*)     (ws + (size_t)4 * 1024 * 1024 + 32768);   // 2048 B
    float*    gsum = (float*)   (ws + (size_t)4 * 1024 * 1024 + 34816);   // 4 B
    int*      gcnt = (int*)     (ws + (size_t)4 * 1024 * 1024 + 34820);   // 4 B
    unsigned* done = (unsigned*)(ws + (size_t)4 * 1024 * 1024 + 34824);   // 4 B
    int*      mem  = (int*)     (ws + (size_t)4 * 1024 * 1024 + 36864);   // 128 KB

    hipMemsetAsync(bcnt, 0, 2048 + 16, stream);          // bcnt + gsum/gcnt/done
    k_norm<<<NROWS / 4, 256, 0, stream>>>(emb, labels, xnb, amax, bcnt, mem);
    dim3 g2(NROWS / 128, NCLS / 64);   // 64 strips x 8 chunks
    k_maxneg<<<g2, 512, 65536, stream>>>(xnb, labels, amax);
    k_cpairs2<<<NCLS, 256, 0, stream>>>(xnb, amax, bcnt, mem, gsum, gcnt, done, out);
}